// Round 1
// baseline (597.824 us; speedup 1.0000x reference)
//
#include <hip/hip_runtime.h>
#include <math.h>

// Problem constants
#define NPTS   131072          // 32*64*64 points
#define DIMS   64              // embedding dim / channels
#define KCODES 512             // codebook size
#define HW     4096            // 64*64 spatial
#define PTS_PER_BLK 64

// d_out flat offsets (floats), reference tuple order:
// (loss, quantized_out[NCHW], perplexity, encodings, quantized_flat)
#define OFF_LOSS 0
#define OFF_QOUT 1
#define OFF_PERP 8388609
#define OFF_ENC  8388610
#define OFF_QF   75497474   // 8388610 + 67108864

// d_ws byte offsets
#define WS_HIST  0          // unsigned[512]                (memset to 0)
#define WS_BLOSS 2048       // float[2048] per-block loss partials
#define WS_EMBT  10240      // float[64*512] transposed codebook
#define WS_NRM   141312     // double[512] ||e_k||^2

// ---------------------------------------------------------------------------
// Prep: embT[d][k] = emb[k][d]; nrm[k] = sum_d emb[k][d]^2 (fp64)
// ---------------------------------------------------------------------------
__global__ void vq_prep(const float* __restrict__ emb,
                        float* __restrict__ embT,
                        double* __restrict__ nrm)
{
    int k = blockIdx.x;      // 512 blocks
    int d = threadIdx.x;     // 64 threads = 1 wave
    float v = emb[k * DIMS + d];
    embT[d * KCODES + k] = v;
    double s = (double)v * (double)v;
    #pragma unroll
    for (int off = 32; off > 0; off >>= 1)
        s += __shfl_down(s, off, 64);
    if (d == 0) nrm[k] = s;
}

// ---------------------------------------------------------------------------
// Main: per-block 64 points. fp64-accumulated distances -> argmin, then all
// output writes fused (one-hot rows written directly: no separate memset).
// ---------------------------------------------------------------------------
__global__ __launch_bounds__(256, 2) void vq_main(
    const float*  __restrict__ in,     // NCHW [32][64][64][64]
    const float*  __restrict__ emb,    // [512][64]
    const float*  __restrict__ embT,   // [64][512]
    const double* __restrict__ nrm,    // [512]
    unsigned*     __restrict__ hist,   // [512]
    float*        __restrict__ bloss,  // [2048]
    float*        __restrict__ out)    // full output
{
    __shared__ double xs[64 * 64];     // [d][p] x-tile, fp64       32 KB
    __shared__ float  es[64 * 64];     // [d][kk] code chunk, fp32  16 KB
    __shared__ double ns[64];          // chunk norms                0.5 KB
    __shared__ float  qs[64 * 65];     // chosen rows [p][d], +1pad 16.25 KB
    __shared__ double rval[64 * 16];   // cross-thread argmin vals    8 KB
    __shared__ int    ridx[64 * 16];   //                             4 KB
    __shared__ int    fidx[64];        // final indices
    // total ~77 KB -> 2 blocks/CU

    const int tid  = threadIdx.x;
    const int lane = tid & 63;
    const int dg   = tid >> 6;

    const int blk = blockIdx.x;          // 2048 blocks
    const int b   = blk >> 6;            // batch
    const int hw0 = (blk & 63) * 64;     // spatial tile start
    const long inBase = (long)b * (DIMS * HW) + hw0;

    // ---- stage x tile: coalesced global, conflict-free LDS ----
    #pragma unroll
    for (int i = 0; i < 16; i++) {
        int d = dg * 16 + i;
        xs[d * 64 + lane] = (double)in[inBase + (long)d * HW + lane];
    }

    const int pg = tid >> 4;   // point group 0..15 (4 points each)
    const int kg = tid & 15;   // code group  0..15 (4 codes each)

    double bestv[4];
    int    besti[4];
    #pragma unroll
    for (int pi = 0; pi < 4; pi++) { bestv[pi] = 1e300; besti[pi] = 0x7fffffff; }

    for (int c = 0; c < 8; c++) {        // 8 chunks of 64 codes
        __syncthreads();
        #pragma unroll
        for (int i = 0; i < 16; i++) {
            int d = dg * 16 + i;
            es[d * 64 + lane] = embT[d * KCODES + c * 64 + lane];
        }
        if (tid < 64) ns[tid] = nrm[c * 64 + tid];
        __syncthreads();

        double acc[4][4] = {};
        #pragma unroll 4
        for (int d = 0; d < 64; d++) {
            double xv[4];
            #pragma unroll
            for (int j = 0; j < 4; j++) xv[j] = xs[d * 64 + pg * 4 + j];
            float4 ev = *(const float4*)&es[d * 64 + kg * 4];
            double ed[4] = { (double)ev.x, (double)ev.y, (double)ev.z, (double)ev.w };
            #pragma unroll
            for (int pi = 0; pi < 4; pi++)
                #pragma unroll
                for (int ki = 0; ki < 4; ki++)
                    acc[pi][ki] = fma(xv[pi], ed[ki], acc[pi][ki]);
        }

        #pragma unroll
        for (int ki = 0; ki < 4; ki++) {
            int k = c * 64 + kg * 4 + ki;
            double nk = ns[kg * 4 + ki];
            #pragma unroll
            for (int pi = 0; pi < 4; pi++) {
                double m = nk - 2.0 * acc[pi][ki];   // ||e||^2 - 2 x.e
                if (m < bestv[pi] || (m == bestv[pi] && k < besti[pi])) {
                    bestv[pi] = m; besti[pi] = k;
                }
            }
        }
    }

    #pragma unroll
    for (int pi = 0; pi < 4; pi++) {
        int p = pg * 4 + pi;
        rval[p * 16 + kg] = bestv[pi];
        ridx[p * 16 + kg] = besti[pi];
    }
    __syncthreads();

    // ---- final per-point reduction, loss partial, histogram ----
    if (tid < 64) {
        int p = tid;
        double bv = rval[p * 16];
        int    bi = ridx[p * 16];
        #pragma unroll
        for (int j = 1; j < 16; j++) {
            double v = rval[p * 16 + j];
            int    ii = ridx[p * 16 + j];
            if (v < bv || (v == bv && ii < bi)) { bv = v; bi = ii; }
        }
        fidx[p] = bi;
        double sx = 0.0;
        for (int d = 0; d < 64; d++) { double v = xs[d * 64 + p]; sx = fma(v, v, sx); }
        double lp = bv + sx;   // ||x - e_best||^2  (>= 0 up to fp noise)
        #pragma unroll
        for (int off = 32; off > 0; off >>= 1)
            lp += __shfl_down(lp, off, 64);
        if (p == 0) bloss[blk] = (float)lp;
        atomicAdd(&hist[bi], 1u);
    }
    __syncthreads();

    // ---- stage chosen embedding rows into padded LDS ----
    {
        int q = tid & 3, p = tid >> 2;
        int row = fidx[p];
        const float4* src = (const float4*)(emb + row * DIMS + q * 16);
        #pragma unroll
        for (int i = 0; i < 4; i++) {
            float4 v = src[i];
            int base = p * 65 + q * 16 + i * 4;
            qs[base] = v.x; qs[base + 1] = v.y; qs[base + 2] = v.z; qs[base + 3] = v.w;
        }
    }
    __syncthreads();

    const int n0 = b * HW + hw0;   // first flat point index of block

    // ---- encodings: write full one-hot rows (zeros + 1.0) coalesced ----
    {
        float* encB = out + (long)OFF_ENC + (long)n0 * KCODES;
        #pragma unroll 4
        for (int i = 0; i < 32; i++) {
            int f  = i * 1024 + tid * 4;
            int p  = f >> 9;
            int k0 = f & 511;
            int fd = fidx[p];
            float4 v;
            v.x = (k0     == fd) ? 1.0f : 0.0f;
            v.y = (k0 + 1 == fd) ? 1.0f : 0.0f;
            v.z = (k0 + 2 == fd) ? 1.0f : 0.0f;
            v.w = (k0 + 3 == fd) ? 1.0f : 0.0f;
            *(float4*)(encB + f) = v;
        }
    }

    // ---- quantized_flat [n][64] ----
    {
        float* qfB = out + (long)OFF_QF + (long)n0 * DIMS;
        #pragma unroll
        for (int i = 0; i < 4; i++) {
            int f = i * 1024 + tid * 4;
            int p = f >> 6;
            int d = f & 63;
            float4 v;
            v.x = qs[p * 65 + d];     v.y = qs[p * 65 + d + 1];
            v.z = qs[p * 65 + d + 2]; v.w = qs[p * 65 + d + 3];
            *(float4*)(qfB + f) = v;
        }
    }

    // ---- quantized_out NCHW (LDS transpose, +65 pad -> conflict-free) ----
    {
        float* qoB = out + (long)OFF_QOUT + (long)b * (DIMS * HW) + hw0;
        #pragma unroll
        for (int i = 0; i < 16; i++) {
            int d = dg * 16 + i;
            qoB[(long)d * HW + lane] = qs[lane * 65 + d];
        }
    }
}

// ---------------------------------------------------------------------------
// Finalize: loss scalar + perplexity (fp64)
// ---------------------------------------------------------------------------
__global__ void vq_finalize(const unsigned* __restrict__ hist,
                            const float* __restrict__ bloss,
                            float* __restrict__ out)
{
    __shared__ double sl[512];
    __shared__ double sh[512];
    int tid = threadIdx.x;   // 512 threads

    double l = (double)bloss[tid] + (double)bloss[tid + 512]
             + (double)bloss[tid + 1024] + (double)bloss[tid + 1536];

    unsigned c = hist[tid];
    double p = (double)c * (1.0 / 131072.0);
    double h = p * log(p + 1e-10);

    sl[tid] = l;
    sh[tid] = h;
    __syncthreads();
    for (int s = 256; s > 0; s >>= 1) {
        if (tid < s) { sl[tid] += sl[tid + s]; sh[tid] += sh[tid + s]; }
        __syncthreads();
    }
    if (tid == 0) {
        out[OFF_LOSS] = (float)(0.25 * sl[0] / 8388608.0);
        out[OFF_PERP] = (float)exp(-sh[0]);
    }
}

// ---------------------------------------------------------------------------
extern "C" void kernel_launch(void* const* d_in, const int* in_sizes, int n_in,
                              void* d_out, int out_size, void* d_ws, size_t ws_size,
                              hipStream_t stream)
{
    const float* in  = (const float*)d_in[0];   // inputs  [32,64,64,64] f32
    const float* emb = (const float*)d_in[1];   // codebook [512,64] f32
    float* out = (float*)d_out;
    char*  ws  = (char*)d_ws;

    unsigned* hist  = (unsigned*)(ws + WS_HIST);
    float*    bloss = (float*)   (ws + WS_BLOSS);
    float*    embT  = (float*)   (ws + WS_EMBT);
    double*   nrm   = (double*)  (ws + WS_NRM);

    hipMemsetAsync(hist, 0, 2048, stream);
    vq_prep<<<KCODES, 64, 0, stream>>>(emb, embT, nrm);
    vq_main<<<NPTS / PTS_PER_BLK, 256, 0, stream>>>(in, emb, embT, nrm, hist, bloss, out);
    vq_finalize<<<1, 512, 0, stream>>>(hist, bloss, out);
}